// Round 5
// baseline (340.467 us; speedup 1.0000x reference)
//
#include <hip/hip_runtime.h>
#include <hip/hip_bf16.h>
#include <stdint.h>

// AWQ GEMM: out[2048,11008](f32 buffer; f16-valued) = x[2048,4096](f32) @ dequant(...) + bias
// Harness dtype model (established rounds 0-4):
//   inputs x/scales/bias: f16 upcast to f32  -> const float*
//   qweight/qzeros: int32                    -> const int*
//   output: reference dtype f16 != bfloat16  -> float*  (THE round-4 fix)
// Kernel structure = round 3 (validated bit-equal to the textbook round-4 build):
// 128x128x64 tiles, reg-staged A (f32->bf16), reg-dequant B, XOR-swizzled LDS,
// single-barrier double-buffer, XCD-aware block swizzle.

constexpr int TOKENS = 2048;
constexpr int IN_F   = 4096;
constexpr int OUT_F  = 11008;
constexpr int PCOLS  = OUT_F / 8;   // 1376
constexpr int BM = 128, BN = 128, BK = 64;
constexpr int NKT    = IN_F / BK;   // 64
constexpr int MTILES = TOKENS / BM; // 16
constexpr int NTILES = OUT_F / BN;  // 86

typedef short short8 __attribute__((ext_vector_type(8)));
typedef float f32x4  __attribute__((ext_vector_type(4)));

__device__ __forceinline__ unsigned int pack_bf16(float a, float b) {
    unsigned int lo = (unsigned int)__builtin_bit_cast(unsigned short, __float2bfloat16(a));
    unsigned int hi = (unsigned int)__builtin_bit_cast(unsigned short, __float2bfloat16(b));
    return lo | (hi << 16);
}

__global__ __launch_bounds__(256)
void awq_gemm_kernel(const float* __restrict__ X,
                     const int*   __restrict__ QW,
                     const int*   __restrict__ QZ,
                     const float* __restrict__ S,
                     const float* __restrict__ BIAS,
                     float*       __restrict__ O)
{
    // double buffer: buf b -> A tile at b*32768 (16KB), B tile at b*32768+16384 (16KB)
    // A layout: row r (0..127) * 128B, 8 x 16B slots; k-octet o at slot o^(r&7)
    // B layout: col n (0..127) * 128B, 8 x 16B slots; k-octet o at slot o^(n&7)^((n>>3)&7)
    __shared__ alignas(16) unsigned char smem[65536];

    const int t    = threadIdx.x;
    const int lane = t & 63;
    const int w    = t >> 6;       // wave 0..3
    const int wrow = w >> 1;       // 0..1
    const int wcol = w & 1;        // 0..1
    const int l15 = lane & 15, l45 = lane >> 4, l7 = lane & 7, l3 = (lane >> 3) & 1;

    // XCD-aware swizzle: XCD x (=bid&7) sweeps all ntiles of mtiles {2x, 2x+1}.
    const int bid   = blockIdx.x;
    const int idx   = bid >> 3;
    const int mtile = (bid & 7) * 2 + idx / NTILES;
    const int ntile = idx % NTILES;
    const int m0 = mtile * BM;
    const int n0 = ntile * BN;
    const int P0 = n0 >> 3;

    // ---- A staging (reg-staged f32 -> bf16; thread t covers rows i*32+(t>>3), k-octet t&7) ----
    const int arow  = t >> 3;                 // 0..31 per chunk
    const int aoct  = t & 7;
    const int aphys = aoct ^ (arow & 7);
    const float* Xb = X + (size_t)(m0 + arow) * IN_F + aoct * 8;

    float4 areg[4][2];
    auto load_A = [&](int kt) {
#pragma unroll
        for (int i = 0; i < 4; ++i) {
            const float* p = Xb + (size_t)i * 32 * IN_F + kt * BK;
            areg[i][0] = *(const float4*)(p);
            areg[i][1] = *(const float4*)(p + 4);
        }
    };
    auto write_A = [&](int buf) {
        unsigned char* ab = smem + buf * 32768;
#pragma unroll
        for (int i = 0; i < 4; ++i) {
            uint4 v;
            v.x = pack_bf16(areg[i][0].x, areg[i][0].y);
            v.y = pack_bf16(areg[i][0].z, areg[i][0].w);
            v.z = pack_bf16(areg[i][1].x, areg[i][1].y);
            v.w = pack_bf16(areg[i][1].z, areg[i][1].w);
            *(uint4*)(ab + (i * 32 + arow) * 128 + aphys * 16) = v;
        }
    };

    // ---- B staging (register dequant; thread covers packed col pcol, k = 4*kq..4*kq+3) ----
    const int pcol = t & 15;
    const int kq   = t >> 4;      // 0..15
    const int* qwbase = QW + (4 * kq) * PCOLS + P0 + pcol;
    const unsigned int* qzbase = (const unsigned int*)(QZ + P0 + pcol);
    const float* sbase = S + n0 + pcol * 8;

    constexpr int SH[8] = {0, 16, 4, 20, 8, 24, 12, 28}; // shift of logical nibble j

    float sf[8], mzs[8];
    unsigned int zraw_n; float4 sv0, sv1;
    unsigned int raw[4];

    auto load_group = [&](int g) {
        zraw_n = qzbase[(size_t)g * PCOLS];
        sv0 = *(const float4*)(sbase + (size_t)g * OUT_F);
        sv1 = *(const float4*)(sbase + (size_t)g * OUT_F + 4);
    };
    auto compute_group = [&]() {
        sf[0] = sv0.x; sf[1] = sv0.y; sf[2] = sv0.z; sf[3] = sv0.w;
        sf[4] = sv1.x; sf[5] = sv1.y; sf[6] = sv1.z; sf[7] = sv1.w;
#pragma unroll
        for (int j = 0; j < 8; ++j) {
            float z = (float)((zraw_n >> SH[j]) & 15u);
            mzs[j] = -z * sf[j];
        }
    };
    auto load_raws = [&](int kt) {
        const int* p = qwbase + (size_t)kt * BK * PCOLS;
#pragma unroll
        for (int kk = 0; kk < 4; ++kk) raw[kk] = (unsigned int)p[(size_t)kk * PCOLS];
    };
    auto stage_B = [&](int buf) {
        unsigned char* bb = smem + buf * 32768 + 16384;
#pragma unroll
        for (int j = 0; j < 8; ++j) {
            float w0 = fmaf((float)((raw[0] >> SH[j]) & 15u), sf[j], mzs[j]);
            float w1 = fmaf((float)((raw[1] >> SH[j]) & 15u), sf[j], mzs[j]);
            float w2 = fmaf((float)((raw[2] >> SH[j]) & 15u), sf[j], mzs[j]);
            float w3 = fmaf((float)((raw[3] >> SH[j]) & 15u), sf[j], mzs[j]);
            unsigned long long v = (unsigned long long)pack_bf16(w0, w1)
                                 | ((unsigned long long)pack_bf16(w2, w3) << 32);
            const int n    = pcol * 8 + j;
            const int slot = (kq >> 1) ^ j ^ (pcol & 7);
            *(unsigned long long*)(bb + n * 128 + slot * 16 + (kq & 1) * 8) = v;
        }
    };

    f32x4 acc[4][4];
#pragma unroll
    for (int mi = 0; mi < 4; ++mi)
#pragma unroll
        for (int ni = 0; ni < 4; ++ni)
            acc[mi][ni] = f32x4{0.f, 0.f, 0.f, 0.f};

    auto compute_tile = [&](int buf) {
        const unsigned char* ab = smem + buf * 32768;
        const unsigned char* bb = smem + buf * 32768 + 16384;
#pragma unroll
        for (int ks = 0; ks < 2; ++ks) {
            short8 a[4], b[4];
#pragma unroll
            for (int mi = 0; mi < 4; ++mi) {
                int off = (wrow * 64 + mi * 16 + l15) * 128
                        + (((ks * 4 + l45) ^ l7) * 16);
                a[mi] = *(const short8*)(ab + off);
            }
#pragma unroll
            for (int ni = 0; ni < 4; ++ni) {
                int off = (wcol * 64 + ni * 16 + l15) * 128
                        + ((((ks * 4 + l45) ^ l7 ^ l3) ^ (2 * ni)) * 16);
                b[ni] = *(const short8*)(bb + off);
            }
#pragma unroll
            for (int mi = 0; mi < 4; ++mi)
#pragma unroll
                for (int ni = 0; ni < 4; ++ni)
                    acc[mi][ni] = __builtin_amdgcn_mfma_f32_16x16x32_bf16(
                        a[mi], b[ni], acc[mi][ni], 0, 0, 0);
        }
    };

    // ---- prologue ----
    load_A(0);
    load_raws(0);
    load_group(0);
    compute_group();
    write_A(0);
    stage_B(0);
    __syncthreads();

    // ---- main loop: single barrier per iter, dbuf ----
#pragma unroll 2
    for (int kt = 0; kt < NKT; ++kt) {
        const int cur = kt & 1;
        if (kt + 1 < NKT) {
            load_A(kt + 1);
            load_raws(kt + 1);
            if (((kt + 1) & 1) == 0) load_group((kt + 1) >> 1);
        }
        compute_tile(cur);
        if (kt + 1 < NKT) {
            if (((kt + 1) & 1) == 0) compute_group();
            write_A(cur ^ 1);
            stage_B(cur ^ 1);
        }
        __syncthreads();
    }

    // ---- epilogue: bias + store as FLOAT32 (C/D: col=lane&15, row=(lane>>4)*4+reg) ----
    const int orow0 = m0 + wrow * 64 + l45 * 4;
    const int ocol0 = n0 + wcol * 64 + l15;
    float bv[4];
#pragma unroll
    for (int ni = 0; ni < 4; ++ni)
        bv[ni] = BIAS[ocol0 + ni * 16];
#pragma unroll
    for (int mi = 0; mi < 4; ++mi)
#pragma unroll
        for (int ni = 0; ni < 4; ++ni)
#pragma unroll
            for (int r = 0; r < 4; ++r) {
                int row = orow0 + mi * 16 + r;
                int col = ocol0 + ni * 16;
                O[(size_t)row * OUT_F + col] = acc[mi][ni][r] + bv[ni];
            }
}

extern "C" void kernel_launch(void* const* d_in, const int* in_sizes, int n_in,
                              void* d_out, int out_size, void* d_ws, size_t ws_size,
                              hipStream_t stream) {
    const float* X  = (const float*)d_in[0];
    const int*   QW = (const int*)d_in[1];
    const int*   QZ = (const int*)d_in[2];
    const float* S  = (const float*)d_in[3];
    const float* Bi = (const float*)d_in[4];
    float*       O  = (float*)d_out;

    dim3 grid(MTILES * NTILES);   // 1376
    dim3 block(256);
    awq_gemm_kernel<<<grid, block, 0, stream>>>(X, QW, QZ, S, Bi, O);
}

// Round 8
// 286.680 us; speedup vs baseline: 1.1876x; 1.1876x over previous
//
#include <hip/hip_runtime.h>
#include <hip/hip_bf16.h>
#include <stdint.h>

// AWQ GEMM: out[2048,11008](f32) = x[2048,4096](f32,f16-valued) @ dequant4(...) + bias
// Round 8 = round 7 + dequant precision fix: w = ((1024+q) - (1024+z)) * s via
// exact pk_sub then pk_mul (round-7's f16-rounded fused offset gave ~0.004/group
// systematic error -> absmax 1.02). W is now bit-identical to the reference's f16 W.
// BM=256 (512 thr, 8 waves), mfma_f32_16x16x32_f16, 96KB dynamic LDS dbuf,
// single-barrier schedule, XCD-aware block mapping (mtile = bid&7).

constexpr int IN_F   = 4096;
constexpr int OUT_F  = 11008;
constexpr int PCOLS  = OUT_F / 8;   // 1376
constexpr int BM = 256, BN = 128, BK = 64;
constexpr int NKT    = IN_F / BK;   // 64
constexpr int NTILES = OUT_F / BN;  // 86
constexpr int ABYTES = BM * BK * 2; // 32768
constexpr int BBYTES = BN * BK * 2; // 16384
constexpr int BUFB   = ABYTES + BBYTES; // 49152
constexpr int LDSTOT = 2 * BUFB;        // 98304

typedef _Float16 h2 __attribute__((ext_vector_type(2)));
typedef _Float16 h8 __attribute__((ext_vector_type(8)));
typedef float f32x4  __attribute__((ext_vector_type(4)));

__device__ __forceinline__ h2 pkh2(float a, float b) {
    return __builtin_bit_cast(h2, __builtin_amdgcn_cvt_pkrtz(a, b));
}
__device__ __forceinline__ unsigned int pk2(float a, float b) {
    return __builtin_bit_cast(unsigned int, __builtin_amdgcn_cvt_pkrtz(a, b));
}

__global__ __launch_bounds__(512, 2)
void awq_gemm_kernel(const float* __restrict__ X,
                     const int*   __restrict__ QW,
                     const int*   __restrict__ QZ,
                     const float* __restrict__ S,
                     const float* __restrict__ BIAS,
                     float*       __restrict__ O)
{
    // buf b at smem + b*49152:  A [256 rows][128B] then B [128 cols][128B]
    // A: k-octet o of row r at 16B slot o^(r&7)
    // B: k-octet o of col n at 16B slot o^(n&7)^((n>>3)&7)
    extern __shared__ unsigned char smem[];

    const int t    = threadIdx.x;
    const int lane = t & 63;
    const int w    = t >> 6;      // 0..7
    const int wm   = w >> 1;      // 0..3 (row block of 64)
    const int wn   = w & 1;       // 0..1 (col block of 64)
    const int l15 = lane & 15, l45 = lane >> 4, l7 = lane & 7, l3 = (lane >> 3) & 1;

    // XCD mapping: XCD x (= bid&7) owns mtile x; sweeps all 86 ntiles. 688 = 8*86.
    const int bid   = blockIdx.x;
    const int mtile = bid & 7;
    const int ntile = bid >> 3;
    const int m0 = mtile * BM;
    const int n0 = ntile * BN;
    const int P0 = n0 >> 3;

    // ---- A staging: thread covers rows (t>>3)+64i, k-octet t&7 ----
    const int arow = t >> 3;              // 0..63
    const int aoct = t & 7;
    const int aphys = aoct ^ (arow & 7);  // 64i preserves row&7
    const float* Xb = X + (size_t)(m0 + arow) * IN_F + aoct * 8;

    float4 areg[4][2];
    auto load_A = [&](int kt) {
#pragma unroll
        for (int i = 0; i < 4; ++i) {
            const float* p = Xb + (size_t)i * 64 * IN_F + kt * BK;
            areg[i][0] = *(const float4*)(p);
            areg[i][1] = *(const float4*)(p + 4);
        }
    };
    auto write_A = [&](int buf) {
        unsigned char* ab = smem + buf * BUFB;
#pragma unroll
        for (int i = 0; i < 4; ++i) {
            uint4 v;
            v.x = pk2(areg[i][0].x, areg[i][0].y);
            v.y = pk2(areg[i][0].z, areg[i][0].w);
            v.z = pk2(areg[i][1].x, areg[i][1].y);
            v.w = pk2(areg[i][1].z, areg[i][1].w);
            *(uint4*)(ab + (i * 64 + arow) * 128 + aphys * 16) = v;
        }
    };

    // ---- B staging: thread covers packed col pcol = t&15, k-pair 2kd, 2kd+1 (kd = t>>4) ----
    const int pcol = t & 15;
    const int kd   = t >> 4;         // 0..31
    const int pc7  = pcol & 7;
    const int ob   = kd >> 2;        // k-octet
    const int sub  = (kd & 3) * 4;   // byte offset within 16B slot
    const int* qwb = QW + (size_t)(2 * kd) * PCOLS + P0 + pcol;
    const unsigned int* qzc = (const unsigned int*)QZ + P0 + pcol;
    const float* scol = S + n0 + pcol * 8;

    constexpr int SH[8]   = {0, 16, 4, 20, 8, 24, 12, 28}; // shift of logical nibble j
    constexpr int JLO[4]  = {0, 4, 1, 5};                  // low-nibble j of byte b

    h2 spk[8], zpk[8];
    unsigned int zraw_n; float4 sv0, sv1;
    unsigned int raw0, raw1;

    auto load_group = [&](int g) {
        zraw_n = qzc[(size_t)g * PCOLS];
        sv0 = *(const float4*)(scol + (size_t)g * OUT_F);
        sv1 = *(const float4*)(scol + (size_t)g * OUT_F + 4);
    };
    auto compute_group = [&]() {
        const float sf[8] = {sv0.x, sv0.y, sv0.z, sv0.w, sv1.x, sv1.y, sv1.z, sv1.w};
#pragma unroll
        for (int j = 0; j < 8; ++j) {
            float zb = 1024.0f + (float)((zraw_n >> SH[j]) & 15u);  // exact in f16
            spk[j] = pkh2(sf[j], sf[j]);
            zpk[j] = pkh2(zb, zb);
        }
    };
    auto load_raws = [&](int kt) {
        const size_t off = (size_t)kt * BK * PCOLS;
        raw0 = (unsigned int)qwb[off];
        raw1 = (unsigned int)qwb[off + PCOLS];
    };
    auto stage_B = [&](int buf) {
        unsigned char* bb = smem + buf * BUFB + ABYTES;
#pragma unroll
        for (int b = 0; b < 4; ++b) {
            const int jl = JLO[b], jh = jl + 2;
            // byte b of raw0 -> dst byte0, byte b of raw1 -> dst byte2 (others masked)
            unsigned int d  = __builtin_amdgcn_perm(raw1, raw0,
                                 (unsigned int)(((4 + b) << 16) | b));
            unsigned int lo = (d & 0x000F000Fu) | 0x64006400u;         // (1024+q) pair, j=jl
            unsigned int hi = ((d >> 4) & 0x000F000Fu) | 0x64006400u;  // j=jh
            // exact sub (both exact ints in f16), then single f16 rounding on mul:
            // bit-identical to reference's (iw - iz) * scales in f16.
            h2 wl = (__builtin_bit_cast(h2, lo) - zpk[jl]) * spk[jl];
            h2 wh = (__builtin_bit_cast(h2, hi) - zpk[jh]) * spk[jh];
            const int nl = pcol * 8 + jl, nh = pcol * 8 + jh;
            *(unsigned int*)(bb + nl * 128 + ((ob ^ jl ^ pc7) * 16) + sub) =
                __builtin_bit_cast(unsigned int, wl);
            *(unsigned int*)(bb + nh * 128 + ((ob ^ jh ^ pc7) * 16) + sub) =
                __builtin_bit_cast(unsigned int, wh);
        }
    };

    f32x4 acc[4][4];
#pragma unroll
    for (int mi = 0; mi < 4; ++mi)
#pragma unroll
        for (int ni = 0; ni < 4; ++ni)
            acc[mi][ni] = f32x4{0.f, 0.f, 0.f, 0.f};

    auto compute_tile = [&](int buf) {
        const unsigned char* ab = smem + buf * BUFB;
        const unsigned char* bb = smem + buf * BUFB + ABYTES;
#pragma unroll
        for (int ks = 0; ks < 2; ++ks) {
            h8 a[4], bf[4];
#pragma unroll
            for (int mi = 0; mi < 4; ++mi) {
                int off = (wm * 64 + mi * 16 + l15) * 128
                        + (((ks * 4 + l45) ^ l7) * 16);
                a[mi] = *(const h8*)(ab + off);
            }
#pragma unroll
            for (int ni = 0; ni < 4; ++ni) {
                int off = (wn * 64 + ni * 16 + l15) * 128
                        + ((((ks * 4 + l45) ^ l7 ^ l3) ^ (2 * ni)) * 16);
                bf[ni] = *(const h8*)(bb + off);
            }
#pragma unroll
            for (int mi = 0; mi < 4; ++mi)
#pragma unroll
                for (int ni = 0; ni < 4; ++ni)
                    acc[mi][ni] = __builtin_amdgcn_mfma_f32_16x16x32_f16(
                        a[mi], bf[ni], acc[mi][ni], 0, 0, 0);
        }
    };

    // ---- prologue ----
    load_A(0);
    load_raws(0);
    load_group(0);
    compute_group();
    write_A(0);
    stage_B(0);
    __syncthreads();

    // ---- main loop: single barrier per iter, dbuf ----
#pragma unroll 2
    for (int kt = 0; kt < NKT; ++kt) {
        const int cur = kt & 1;
        if (kt + 1 < NKT) {
            load_A(kt + 1);                    // issue-early (T14)
            load_raws(kt + 1);
            if (((kt + 1) & 1) == 0) load_group((kt + 1) >> 1);
        }
        compute_tile(cur);
        if (kt + 1 < NKT) {
            if (((kt + 1) & 1) == 0) compute_group();
            write_A(cur ^ 1);
            stage_B(cur ^ 1);
        }
        __syncthreads();
    }

    // ---- epilogue: bias + f32 store (C/D: col=lane&15, row=(lane>>4)*4+reg) ----
    const int orow0 = m0 + wm * 64 + l45 * 4;
    const int ocol0 = n0 + wn * 64 + l15;
    float bv[4];
#pragma unroll
    for (int ni = 0; ni < 4; ++ni)
        bv[ni] = BIAS[ocol0 + ni * 16];
#pragma unroll
    for (int mi = 0; mi < 4; ++mi)
#pragma unroll
        for (int ni = 0; ni < 4; ++ni)
#pragma unroll
            for (int r = 0; r < 4; ++r) {
                int row = orow0 + mi * 16 + r;
                int col = ocol0 + ni * 16;
                O[(size_t)row * OUT_F + col] = acc[mi][ni][r] + bv[ni];
            }
}

extern "C" void kernel_launch(void* const* d_in, const int* in_sizes, int n_in,
                              void* d_out, int out_size, void* d_ws, size_t ws_size,
                              hipStream_t stream) {
    const float* X  = (const float*)d_in[0];
    const int*   QW = (const int*)d_in[1];
    const int*   QZ = (const int*)d_in[2];
    const float* S  = (const float*)d_in[3];
    const float* Bi = (const float*)d_in[4];
    float*       O  = (float*)d_out;

    dim3 grid(8 * NTILES);   // 688
    dim3 block(512);
    awq_gemm_kernel<<<grid, block, LDSTOT, stream>>>(X, QW, QZ, S, Bi, O);
}